// Round 1
// baseline (1923.970 us; speedup 1.0000x reference)
//
#include <hip/hip_runtime.h>
#include <hip/hip_bf16.h>
#include <math.h>

// Problem constants (fixed by reference)
#define DD    1024
#define NHEAD 16
#define HDIM  64
#define TLEN  2048
#define SLEN  2048
#define BSZ   2
#define NBH   (BSZ*NHEAD)   // 32
#define GROWS (TLEN*BSZ)    // 4096

// Workspace layout (floats). Requires ws_size >= 67,633,152 bytes.
//  Qp [B][H][T][64]  scaled by 0.125     @ 0
//  Kp [B][H][S][64]                      @ 4194304
//  Vp [B][H][S][64]                      @ 8388608
//  Op [T*B][1024]   attention out        @ 12582912
//  Ml [B*H*T]                            @ 16777216
//  Ll [B*H*T]                            @ 16842752

// ---------------- GEMM: Y = (X @ W^T + bias) * scale ----------------
// X: [4096][1024] row-major; W: [1024][1024] row-major (out,in) -> row-dot-row.
// qkv_mode=1: scatter to [B][H][T][64]; qkv_mode=0: plain [r][c].
#define GBM 128
#define GBN 128
#define GBK 16

__global__ __launch_bounds__(256) void gemm_xwt(
        const float* __restrict__ X, const float* __restrict__ W,
        const float* __restrict__ bias, float* __restrict__ Y,
        float scale, int qkv_mode) {
    // Transposed tiles: [k][row], pad +4 keeps b128 reads conflict-light.
    __shared__ float Xs[GBK][GBM + 4];
    __shared__ float Ws[GBK][GBN + 4];
    const int tid = threadIdx.x;
    const int tx = tid & 15, ty = tid >> 4;
    const int r0 = blockIdx.y * GBM, c0 = blockIdx.x * GBN;

    float acc[8][8];
    #pragma unroll
    for (int i = 0; i < 8; ++i)
        #pragma unroll
        for (int j = 0; j < 8; ++j) acc[i][j] = 0.f;

    for (int k0 = 0; k0 < DD; k0 += GBK) {
        #pragma unroll
        for (int it = 0; it < 2; ++it) {
            int slot = it * 256 + tid;          // 0..511
            int row = slot >> 2;                // 0..127
            int ks  = (slot & 3) << 2;          // 0,4,8,12
            float4 xv = *(const float4*)&X[(size_t)(r0 + row) * DD + k0 + ks];
            Xs[ks+0][row] = xv.x; Xs[ks+1][row] = xv.y;
            Xs[ks+2][row] = xv.z; Xs[ks+3][row] = xv.w;
            float4 wv = *(const float4*)&W[(size_t)(c0 + row) * DD + k0 + ks];
            Ws[ks+0][row] = wv.x; Ws[ks+1][row] = wv.y;
            Ws[ks+2][row] = wv.z; Ws[ks+3][row] = wv.w;
        }
        __syncthreads();
        #pragma unroll
        for (int kk = 0; kk < GBK; ++kk) {
            float4 xa = *(const float4*)&Xs[kk][8*ty];
            float4 xb = *(const float4*)&Xs[kk][8*ty + 4];
            float4 wa = *(const float4*)&Ws[kk][8*tx];
            float4 wb = *(const float4*)&Ws[kk][8*tx + 4];
            float xr[8] = {xa.x,xa.y,xa.z,xa.w,xb.x,xb.y,xb.z,xb.w};
            float wr[8] = {wa.x,wa.y,wa.z,wa.w,wb.x,wb.y,wb.z,wb.w};
            #pragma unroll
            for (int i = 0; i < 8; ++i)
                #pragma unroll
                for (int j = 0; j < 8; ++j)
                    acc[i][j] = fmaf(xr[i], wr[j], acc[i][j]);
        }
        __syncthreads();
    }

    #pragma unroll
    for (int i = 0; i < 8; ++i) {
        const int r = r0 + 8*ty + i;
        const int t = r >> 1, bb = r & 1;       // r = t*B + b, B=2
        #pragma unroll
        for (int jj = 0; jj < 2; ++jj) {
            const int c = c0 + 8*tx + 4*jj;     // 4-aligned, never straddles h boundary
            float4 v;
            v.x = (acc[i][4*jj+0] + bias[c+0]) * scale;
            v.y = (acc[i][4*jj+1] + bias[c+1]) * scale;
            v.z = (acc[i][4*jj+2] + bias[c+2]) * scale;
            v.w = (acc[i][4*jj+3] + bias[c+3]) * scale;
            if (qkv_mode) {
                const int h = c >> 6, d = c & 63;
                *(float4*)&Y[(size_t)((bb*NHEAD + h)*TLEN + t)*HDIM + d] = v;
            } else {
                *(float4*)&Y[(size_t)r * DD + c] = v;
            }
        }
    }
}

// ---------------- Attention pass 1: row max m and denom l ----------------
#define ATT 128   // t-rows per block
#define ASS 64    // s-cols per tile

__global__ __launch_bounds__(256) void att_ml(
        const float* __restrict__ Qp, const float* __restrict__ Kp,
        float* __restrict__ Ml, float* __restrict__ Ll) {
    __shared__ float QsT[HDIM][ATT + 4];   // [d][t-row]
    __shared__ float KsT[HDIM][ASS + 4];   // [d][s-col]
    const int tid = threadIdx.x;
    const int tx = tid & 15, ty = tid >> 4;
    const int bh = blockIdx.y;
    const int t0 = blockIdx.x * ATT;
    const float* Qb = Qp + (size_t)bh * TLEN * HDIM;
    const float* Kb = Kp + (size_t)bh * SLEN * HDIM;

    #pragma unroll
    for (int it = 0; it < 8; ++it) {
        int slot = it * 256 + tid;            // 0..2047
        int row = slot >> 4, ds = (slot & 15) << 2;
        float4 qv = *(const float4*)&Qb[(size_t)(t0 + row) * HDIM + ds];
        QsT[ds+0][row] = qv.x; QsT[ds+1][row] = qv.y;
        QsT[ds+2][row] = qv.z; QsT[ds+3][row] = qv.w;
    }

    float m[8], l[8];
    #pragma unroll
    for (int i = 0; i < 8; ++i) { m[i] = -3.0e38f; l[i] = 0.f; }

    for (int s0 = 0; s0 < SLEN; s0 += ASS) {
        __syncthreads();
        #pragma unroll
        for (int it = 0; it < 4; ++it) {
            int slot = it * 256 + tid;        // 0..1023
            int row = slot >> 4, ds = (slot & 15) << 2;
            float4 kv = *(const float4*)&Kb[(size_t)(s0 + row) * HDIM + ds];
            KsT[ds+0][row] = kv.x; KsT[ds+1][row] = kv.y;
            KsT[ds+2][row] = kv.z; KsT[ds+3][row] = kv.w;
        }
        __syncthreads();

        float sc[8][4];
        #pragma unroll
        for (int i = 0; i < 8; ++i)
            #pragma unroll
            for (int j = 0; j < 4; ++j) sc[i][j] = 0.f;

        #pragma unroll 4
        for (int d = 0; d < HDIM; ++d) {
            float4 qa = *(const float4*)&QsT[d][8*ty];
            float4 qb = *(const float4*)&QsT[d][8*ty + 4];
            float4 kf = *(const float4*)&KsT[d][4*tx];
            float qr[8] = {qa.x,qa.y,qa.z,qa.w,qb.x,qb.y,qb.z,qb.w};
            float kr[4] = {kf.x,kf.y,kf.z,kf.w};
            #pragma unroll
            for (int i = 0; i < 8; ++i)
                #pragma unroll
                for (int j = 0; j < 4; ++j)
                    sc[i][j] = fmaf(qr[i], kr[j], sc[i][j]);
        }

        #pragma unroll
        for (int i = 0; i < 8; ++i) {
            float tm = fmaxf(fmaxf(sc[i][0], sc[i][1]), fmaxf(sc[i][2], sc[i][3]));
            #pragma unroll
            for (int o = 1; o < 16; o <<= 1) tm = fmaxf(tm, __shfl_xor(tm, o, 16));
            float mn = fmaxf(m[i], tm);
            float ts = __expf(sc[i][0]-mn) + __expf(sc[i][1]-mn)
                     + __expf(sc[i][2]-mn) + __expf(sc[i][3]-mn);
            #pragma unroll
            for (int o = 1; o < 16; o <<= 1) ts += __shfl_xor(ts, o, 16);
            l[i] = l[i] * __expf(m[i] - mn) + ts;
            m[i] = mn;
        }
    }

    if (tx == 0) {
        #pragma unroll
        for (int i = 0; i < 8; ++i) {
            int t = t0 + 8*ty + i;
            Ml[(size_t)bh * TLEN + t] = m[i];
            Ll[(size_t)bh * TLEN + t] = l[i];
        }
    }
}

// ---------------- Attention pass 2: O = softmax(QK^T) V ----------------
__global__ __launch_bounds__(256) void att_o(
        const float* __restrict__ Qp, const float* __restrict__ Kp,
        const float* __restrict__ Vp, const float* __restrict__ Ml,
        const float* __restrict__ Ll, float* __restrict__ Op) {
    __shared__ float QsT[HDIM][ATT + 4];   // [d][t-row]
    __shared__ float KV [HDIM][ASS + 4];   // K as [d][s]; reused as V [s][d]
    __shared__ float pT [ASS][ATT + 4];    // [s][t-row]
    const int tid = threadIdx.x;
    const int tx = tid & 15, ty = tid >> 4;
    const int bh = blockIdx.y;
    const int b = bh >> 4, h = bh & 15;
    const int t0 = blockIdx.x * ATT;
    const float* Qb = Qp + (size_t)bh * TLEN * HDIM;
    const float* Kb = Kp + (size_t)bh * SLEN * HDIM;
    const float* Vb = Vp + (size_t)bh * SLEN * HDIM;

    #pragma unroll
    for (int it = 0; it < 8; ++it) {
        int slot = it * 256 + tid;
        int row = slot >> 4, ds = (slot & 15) << 2;
        float4 qv = *(const float4*)&Qb[(size_t)(t0 + row) * HDIM + ds];
        QsT[ds+0][row] = qv.x; QsT[ds+1][row] = qv.y;
        QsT[ds+2][row] = qv.z; QsT[ds+3][row] = qv.w;
    }

    float m[8], il[8];
    #pragma unroll
    for (int i = 0; i < 8; ++i) {
        int t = t0 + 8*ty + i;
        m[i]  = Ml[(size_t)bh * TLEN + t];
        il[i] = 1.f / Ll[(size_t)bh * TLEN + t];
    }

    float O[8][4];
    #pragma unroll
    for (int i = 0; i < 8; ++i)
        #pragma unroll
        for (int j = 0; j < 4; ++j) O[i][j] = 0.f;

    for (int s0 = 0; s0 < SLEN; s0 += ASS) {
        __syncthreads();                       // prev PV done reading KV/pT
        #pragma unroll
        for (int it = 0; it < 4; ++it) {       // K transposed -> KV[d][s]
            int slot = it * 256 + tid;
            int row = slot >> 4, ds = (slot & 15) << 2;
            float4 kv = *(const float4*)&Kb[(size_t)(s0 + row) * HDIM + ds];
            KV[ds+0][row] = kv.x; KV[ds+1][row] = kv.y;
            KV[ds+2][row] = kv.z; KV[ds+3][row] = kv.w;
        }
        __syncthreads();

        float sc[8][4];
        #pragma unroll
        for (int i = 0; i < 8; ++i)
            #pragma unroll
            for (int j = 0; j < 4; ++j) sc[i][j] = 0.f;

        #pragma unroll 4
        for (int d = 0; d < HDIM; ++d) {
            float4 qa = *(const float4*)&QsT[d][8*ty];
            float4 qb = *(const float4*)&QsT[d][8*ty + 4];
            float4 kf = *(const float4*)&KV[d][4*tx];
            float qr[8] = {qa.x,qa.y,qa.z,qa.w,qb.x,qb.y,qb.z,qb.w};
            float kr[4] = {kf.x,kf.y,kf.z,kf.w};
            #pragma unroll
            for (int i = 0; i < 8; ++i)
                #pragma unroll
                for (int j = 0; j < 4; ++j)
                    sc[i][j] = fmaf(qr[i], kr[j], sc[i][j]);
        }

        float p[8][4];
        #pragma unroll
        for (int i = 0; i < 8; ++i)
            #pragma unroll
            for (int j = 0; j < 4; ++j)
                p[i][j] = __expf(sc[i][j] - m[i]) * il[i];

        __syncthreads();                       // scores done reading KV; pT free
        #pragma unroll
        for (int jj = 0; jj < 4; ++jj) {       // pT[s][r], vectorized over r
            int s = 4*tx + jj;
            *(float4*)&pT[s][8*ty]     = make_float4(p[0][jj], p[1][jj], p[2][jj], p[3][jj]);
            *(float4*)&pT[s][8*ty + 4] = make_float4(p[4][jj], p[5][jj], p[6][jj], p[7][jj]);
        }
        #pragma unroll
        for (int it = 0; it < 4; ++it) {       // V direct -> KV[s][d]
            int slot = it * 256 + tid;
            int row = slot >> 4, ds = (slot & 15) << 2;
            *(float4*)&KV[row][ds] = *(const float4*)&Vb[(size_t)(s0 + row) * HDIM + ds];
        }
        __syncthreads();

        #pragma unroll 4
        for (int s = 0; s < ASS; ++s) {
            float4 pa = *(const float4*)&pT[s][8*ty];
            float4 pb = *(const float4*)&pT[s][8*ty + 4];
            float4 vv = *(const float4*)&KV[s][4*tx];
            float pr[8] = {pa.x,pa.y,pa.z,pa.w,pb.x,pb.y,pb.z,pb.w};
            float vr[4] = {vv.x,vv.y,vv.z,vv.w};
            #pragma unroll
            for (int i = 0; i < 8; ++i)
                #pragma unroll
                for (int j = 0; j < 4; ++j)
                    O[i][j] = fmaf(pr[i], vr[j], O[i][j]);
        }
    }

    #pragma unroll
    for (int i = 0; i < 8; ++i) {
        int t = t0 + 8*ty + i;
        *(float4*)&Op[(size_t)(t*BSZ + b) * DD + h*HDIM + 4*tx] =
            make_float4(O[i][0], O[i][1], O[i][2], O[i][3]);
    }
}

// ---------------- attn_avg[b][t][s] = (1/H) sum_h p ----------------
__global__ __launch_bounds__(256) void att_avg(
        const float* __restrict__ Qp, const float* __restrict__ Kp,
        const float* __restrict__ Ml, const float* __restrict__ Ll,
        float* __restrict__ avg) {
    __shared__ float QsT[HDIM][ATT + 4];
    __shared__ float KsT[HDIM][ASS + 4];
    const int tid = threadIdx.x;
    const int tx = tid & 15, ty = tid >> 4;
    const int b  = blockIdx.z;
    const int t0 = blockIdx.y * ATT;
    const int s0 = blockIdx.x * ASS;

    float acc[8][4];
    #pragma unroll
    for (int i = 0; i < 8; ++i)
        #pragma unroll
        for (int j = 0; j < 4; ++j) acc[i][j] = 0.f;

    for (int h = 0; h < NHEAD; ++h) {
        const int bh = b * NHEAD + h;
        const float* Qb = Qp + (size_t)bh * TLEN * HDIM;
        const float* Kb = Kp + (size_t)bh * SLEN * HDIM;
        __syncthreads();
        #pragma unroll
        for (int it = 0; it < 8; ++it) {
            int slot = it * 256 + tid;
            int row = slot >> 4, ds = (slot & 15) << 2;
            float4 qv = *(const float4*)&Qb[(size_t)(t0 + row) * HDIM + ds];
            QsT[ds+0][row] = qv.x; QsT[ds+1][row] = qv.y;
            QsT[ds+2][row] = qv.z; QsT[ds+3][row] = qv.w;
        }
        #pragma unroll
        for (int it = 0; it < 4; ++it) {
            int slot = it * 256 + tid;
            int row = slot >> 4, ds = (slot & 15) << 2;
            float4 kv = *(const float4*)&Kb[(size_t)(s0 + row) * HDIM + ds];
            KsT[ds+0][row] = kv.x; KsT[ds+1][row] = kv.y;
            KsT[ds+2][row] = kv.z; KsT[ds+3][row] = kv.w;
        }
        __syncthreads();

        float sc[8][4];
        #pragma unroll
        for (int i = 0; i < 8; ++i)
            #pragma unroll
            for (int j = 0; j < 4; ++j) sc[i][j] = 0.f;

        #pragma unroll 4
        for (int d = 0; d < HDIM; ++d) {
            float4 qa = *(const float4*)&QsT[d][8*ty];
            float4 qb = *(const float4*)&QsT[d][8*ty + 4];
            float4 kf = *(const float4*)&KsT[d][4*tx];
            float qr[8] = {qa.x,qa.y,qa.z,qa.w,qb.x,qb.y,qb.z,qb.w};
            float kr[4] = {kf.x,kf.y,kf.z,kf.w};
            #pragma unroll
            for (int i = 0; i < 8; ++i)
                #pragma unroll
                for (int j = 0; j < 4; ++j)
                    sc[i][j] = fmaf(qr[i], kr[j], sc[i][j]);
        }

        #pragma unroll
        for (int i = 0; i < 8; ++i) {
            int t = t0 + 8*ty + i;
            float mm  = Ml[(size_t)bh * TLEN + t];
            float ili = 1.f / Ll[(size_t)bh * TLEN + t];
            #pragma unroll
            for (int j = 0; j < 4; ++j)
                acc[i][j] += __expf(sc[i][j] - mm) * ili;
        }
    }

    const float invh = 1.f / NHEAD;
    #pragma unroll
    for (int i = 0; i < 8; ++i) {
        int t = t0 + 8*ty + i;
        *(float4*)&avg[(size_t)(b*TLEN + t) * SLEN + s0 + 4*tx] =
            make_float4(acc[i][0]*invh, acc[i][1]*invh, acc[i][2]*invh, acc[i][3]*invh);
    }
}

// ---------------- host launcher ----------------
extern "C" void kernel_launch(void* const* d_in, const int* in_sizes, int n_in,
                              void* d_out, int out_size, void* d_ws, size_t ws_size,
                              hipStream_t stream) {
    (void)in_sizes; (void)n_in; (void)out_size; (void)ws_size;
    const float* query = (const float*)d_in[0];
    const float* key_  = (const float*)d_in[1];
    const float* value = (const float*)d_in[2];
    const float* Wq = (const float*)d_in[3];  const float* bq = (const float*)d_in[4];
    const float* Wk = (const float*)d_in[5];  const float* bk = (const float*)d_in[6];
    const float* Wv = (const float*)d_in[7];  const float* bv = (const float*)d_in[8];
    const float* Wo = (const float*)d_in[9];  const float* bo = (const float*)d_in[10];

    float* out = (float*)d_out;               // Z at 0 (4194304), avg at 4194304
    float* ws  = (float*)d_ws;                // needs >= 67,633,152 bytes
    float* Qp = ws;
    float* Kp = ws + 4194304;
    float* Vp = ws + 8388608;
    float* Op = ws + 12582912;
    float* Ml = ws + 16777216;
    float* Ll = ws + 16842752;

    const dim3 blk(256);
    const dim3 gemm_grid(DD / GBN, GROWS / GBM);      // (8, 32)
    const float scaling = 0.125f;                     // HD^-0.5

    gemm_xwt<<<gemm_grid, blk, 0, stream>>>(query, Wq, bq, Qp, scaling, 1);
    gemm_xwt<<<gemm_grid, blk, 0, stream>>>(key_,  Wk, bk, Kp, 1.0f,    1);
    gemm_xwt<<<gemm_grid, blk, 0, stream>>>(value, Wv, bv, Vp, 1.0f,    1);

    att_ml <<<dim3(TLEN/ATT, NBH), blk, 0, stream>>>(Qp, Kp, Ml, Ll);
    att_o  <<<dim3(TLEN/ATT, NBH), blk, 0, stream>>>(Qp, Kp, Vp, Ml, Ll, Op);
    att_avg<<<dim3(SLEN/ASS, TLEN/ATT, BSZ), blk, 0, stream>>>(Qp, Kp, Ml, Ll, out + 4194304);

    gemm_xwt<<<gemm_grid, blk, 0, stream>>>(Op, Wo, bo, out, 1.0f, 0);
}

// Round 3
// 361.663 us; speedup vs baseline: 5.3198x; 5.3198x over previous
//
#include <hip/hip_runtime.h>
#include <hip/hip_bf16.h>
#include <math.h>

// Problem constants
#define DD    1024
#define NHEAD 16
#define HDIM  64
#define TLEN  2048
#define SLEN  2048
#define BSZ   2
#define NBH   (BSZ*NHEAD)   // 32
#define GROWS (TLEN*BSZ)    // 4096

typedef _Float16 half8 __attribute__((ext_vector_type(8)));
typedef _Float16 half4v __attribute__((ext_vector_type(4)));
typedef float f32x4 __attribute__((ext_vector_type(4)));

#define MFMA16(a,b,c) __builtin_amdgcn_mfma_f32_16x16x32_f16((a),(b),(c),0,0,0)

// async global->LDS, 16B per lane. LDS dest must be linear (wave-uniform base + lane*16).
#define GLD16(g, l) __builtin_amdgcn_global_load_lds( \
    (const __attribute__((address_space(1))) unsigned int*)(g), \
    (__attribute__((address_space(3))) unsigned int*)(l), 16, 0, 0)

// XOR swizzle within a 128-byte row: permutes 16B blocks by row&7 (bijective involution).
__device__ __forceinline__ int swz(int row, int col2) { return col2 ^ ((row & 7) << 4); }

// ---------------- fp32 -> f16 convert ----------------
__global__ __launch_bounds__(256) void convk(const float* __restrict__ s,
                                             _Float16* __restrict__ d, int n8) {
    int i = blockIdx.x * 256 + threadIdx.x;
    if (i >= n8) return;
    const float4* s4 = (const float4*)s;
    float4 a = s4[2*i], b = s4[2*i+1];
    half8 v;
    v[0]=(_Float16)a.x; v[1]=(_Float16)a.y; v[2]=(_Float16)a.z; v[3]=(_Float16)a.w;
    v[4]=(_Float16)b.x; v[5]=(_Float16)b.y; v[6]=(_Float16)b.z; v[7]=(_Float16)b.w;
    *(half8*)&d[8*i] = v;
}

// ---------------- f16 MFMA GEMM: Y = (A @ W^T + bias) * scale ----------------
// A [4096][1024] f16 row-major; W [1024][1024] f16 row-major ([out][in] -> k-contig = B^T form).
// 128x128 tile, BK=32, 256 thr / 4 waves, each wave 64x64 (4x4 16x16 frags). m97 structure.
__global__ __launch_bounds__(256) void gemm16(const _Float16* __restrict__ A,
        const _Float16* __restrict__ Bw, const float* __restrict__ bias,
        void* __restrict__ Yp, float scale, int f32out) {
    __shared__ _Float16 As[128*32];
    __shared__ _Float16 Bs[128*32];
    const int tid = threadIdx.x;
    const int lane = tid & 63, w = tid >> 6;
    const int l15 = lane & 15, g = lane >> 4;
    const int m0 = blockIdx.y * 128, n0 = blockIdx.x * 128;
    const int wm = (w >> 1) * 64, wn = (w & 1) * 64;

    f32x4 acc[4][4];
    #pragma unroll
    for (int i = 0; i < 4; ++i)
        #pragma unroll
        for (int j = 0; j < 4; ++j) acc[i][j] = (f32x4){0.f,0.f,0.f,0.f};

    for (int kt = 0; kt < DD/32; ++kt) {
        #pragma unroll
        for (int it = 0; it < 2; ++it) {
            int X = (it*256 + tid) * 16;        // byte offset in 8KB tile
            int row = X >> 6, xin = X & 63;     // 64B rows (32 f16)
            GLD16(A  + (size_t)(m0+row)*DD + kt*32 + (xin>>1), (char*)As + X);
            GLD16(Bw + (size_t)(n0+row)*DD + kt*32 + (xin>>1), (char*)Bs + X);
        }
        __syncthreads();
        half8 af[4], bf[4];
        #pragma unroll
        for (int i = 0; i < 4; ++i)
            af[i] = *(const half8*)((const char*)As + (wm+16*i+l15)*64 + 16*g);
        #pragma unroll
        for (int j = 0; j < 4; ++j)
            bf[j] = *(const half8*)((const char*)Bs + (wn+16*j+l15)*64 + 16*g);
        #pragma unroll
        for (int i = 0; i < 4; ++i)
            #pragma unroll
            for (int j = 0; j < 4; ++j)
                acc[i][j] = MFMA16(af[i], bf[j], acc[i][j]);
        __syncthreads();
    }

    #pragma unroll
    for (int j = 0; j < 4; ++j) {
        int c = n0 + wn + 16*j + l15;
        float bj = bias[c];
        #pragma unroll
        for (int i = 0; i < 4; ++i) {
            #pragma unroll
            for (int r = 0; r < 4; ++r) {
                int rr = m0 + wm + 16*i + 4*g + r;
                float y = (acc[i][j][r] + bj) * scale;
                if (f32out) ((float*)Yp)[(size_t)rr*DD + c] = y;
                else        ((_Float16*)Yp)[(size_t)rr*DD + c] = (_Float16)y;
            }
        }
    }
}

// ---------------- V transpose: Vp [s*2+b][1024] -> Vt [bh][d=64][2048 s] ----------------
__global__ __launch_bounds__(256) void transv(const _Float16* __restrict__ Vp,
                                              _Float16* __restrict__ Vt) {
    __shared__ _Float16 Ts[64*64];   // [s][d] swizzled, 128B rows
    const int tid = threadIdx.x;
    const int s0 = blockIdx.x * 64, bh = blockIdx.y;
    const int b = bh >> 4, h = bh & 15;
    #pragma unroll
    for (int it = 0; it < 2; ++it) {
        int X = (it*256 + tid) * 16;
        int row = X >> 7, xin = X & 127;
        int col2 = swz(row, xin);              // pre-swizzled source (rule 21)
        GLD16(Vp + (size_t)((s0+row)*2 + b)*DD + h*64 + (col2>>1), (char*)Ts + X);
    }
    __syncthreads();
    const int d = tid >> 2, sp = tid & 3;
    unsigned int wb[8];
    #pragma unroll
    for (int k = 0; k < 16; ++k) {
        int s = sp*16 + k;
        unsigned short u = *(const unsigned short*)((const char*)Ts + s*128 + swz(s, d*2));
        if (k & 1) wb[k>>1] |= ((unsigned int)u) << 16;
        else       wb[k>>1] = u;
    }
    unsigned int* op = (unsigned int*)(Vt + ((size_t)bh*64 + d)*SLEN + s0 + sp*16);
    ((uint4*)op)[0] = make_uint4(wb[0],wb[1],wb[2],wb[3]);
    ((uint4*)op)[1] = make_uint4(wb[4],wb[5],wb[6],wb[7]);
}

// ---------------- Flash attention: O = softmax(QK^T)V, writes Op f16, Ml, Il ----------------
// Block: 4 waves, 128 t-rows (32/wave). Swapped QK^T: sc = mfma(K,Q) -> D[s][t], lane: t=lane&15.
// P packed in-register to f16, fed to PV as B-operand vs A=V^T with consistent k-slot permutation.
__global__ __launch_bounds__(256) void att_o(const _Float16* __restrict__ Qp,
        const _Float16* __restrict__ Kp, const _Float16* __restrict__ Vt,
        _Float16* __restrict__ Op, float* __restrict__ Ml, float* __restrict__ Il) {
    __shared__ char smem[32768];
    _Float16* Ks  = (_Float16*)smem;            // [64 s][64 d] swizzled, 8KB
    _Float16* Vts = (_Float16*)(smem + 8192);   // [64 d][64 s] swizzled, 8KB
    const int tid = threadIdx.x;
    const int lane = tid & 63, w = tid >> 6;
    const int l15 = lane & 15, g = lane >> 4;
    const int bh = blockIdx.y, b = bh >> 4, h = bh & 15;
    const int t0 = blockIdx.x * 128;

    // Q fragments in registers (B-operand: lane holds t=lane&15+16nf, d = 8g+e+32kq)
    half8 qf[2][2];
    #pragma unroll
    for (int nf = 0; nf < 2; ++nf) {
        int t = t0 + w*32 + 16*nf + l15;
        #pragma unroll
        for (int kq = 0; kq < 2; ++kq)
            qf[nf][kq] = *(const half8*)(Qp + (size_t)(t*2+b)*DD + h*64 + 8*g + 32*kq);
    }

    float m[2] = {-1e30f, -1e30f}, l[2] = {0.f, 0.f};
    f32x4 O[4][2];
    #pragma unroll
    for (int dm = 0; dm < 4; ++dm)
        #pragma unroll
        for (int nf = 0; nf < 2; ++nf) O[dm][nf] = (f32x4){0.f,0.f,0.f,0.f};

    for (int s0 = 0; s0 < SLEN; s0 += 64) {
        #pragma unroll
        for (int it = 0; it < 2; ++it) {       // stage K (8KB) + Vt (8KB)
            int X = (it*256 + tid) * 16;
            int row = X >> 7, xin = X & 127;
            int col2 = swz(row, xin);
            GLD16(Kp + (size_t)((s0+row)*2 + b)*DD + h*64 + (col2>>1), (char*)Ks + X);
            GLD16(Vt + ((size_t)bh*64 + row)*SLEN + s0 + (col2>>1), (char*)Vts + X);
        }
        __syncthreads();

        // QK^T swapped: sc[mf][nf] = K-rows x Q-cols
        f32x4 sc[4][2];
        #pragma unroll
        for (int mf = 0; mf < 4; ++mf) {
            int srow = 16*mf + l15, sw = (srow & 7) << 4;
            half8 k0 = *(const half8*)((const char*)Ks + srow*128 + ((16*g) ^ sw));
            half8 k1 = *(const half8*)((const char*)Ks + srow*128 + ((64 + 16*g) ^ sw));
            #pragma unroll
            for (int nf = 0; nf < 2; ++nf) {
                f32x4 z = (f32x4){0.f,0.f,0.f,0.f};
                z = MFMA16(k0, qf[nf][0], z);
                z = MFMA16(k1, qf[nf][1], z);
                sc[mf][nf] = z;
            }
        }

        // online softmax per t (t = lane&15 + 16nf); s spread over (g, mf, r)
        half8 pbf[2][2];
        #pragma unroll
        for (int nf = 0; nf < 2; ++nf) {
            float mx = -1e30f;
            #pragma unroll
            for (int mf = 0; mf < 4; ++mf)
                #pragma unroll
                for (int r = 0; r < 4; ++r) mx = fmaxf(mx, sc[mf][nf][r]);
            mx = fmaxf(mx, __shfl_xor(mx, 16));
            mx = fmaxf(mx, __shfl_xor(mx, 32));
            float mn = fmaxf(m[nf], mx);
            float corr = __expf(m[nf] - mn);
            float pr[4][4];
            float rs = 0.f;
            #pragma unroll
            for (int mf = 0; mf < 4; ++mf)
                #pragma unroll
                for (int r = 0; r < 4; ++r) {
                    pr[mf][r] = __expf(sc[mf][nf][r] - mn);
                    rs += pr[mf][r];
                }
            rs += __shfl_xor(rs, 16);
            rs += __shfl_xor(rs, 32);
            l[nf] = l[nf] * corr + rs;
            m[nf] = mn;
            #pragma unroll
            for (int dm = 0; dm < 4; ++dm) O[dm][nf] *= corr;
            // pack p -> f16: PV-MFMA kv covers s=32kv..32kv+31; elems e<4 -> mf=2kv (s=32kv+4g+e),
            // e>=4 -> mf=2kv+1 (s=32kv+16+4g+(e-4))
            #pragma unroll
            for (int kv = 0; kv < 2; ++kv) {
                half8 pb;
                #pragma unroll
                for (int e = 0; e < 4; ++e) {
                    pb[e]   = (_Float16)pr[2*kv][e];
                    pb[4+e] = (_Float16)pr[2*kv+1][e];
                }
                pbf[nf][kv] = pb;
            }
        }

        // PV: O^T[d][t] += V^T[d][s] * P^T[s][t], same k-slot permutation on A side
        #pragma unroll
        for (int dm = 0; dm < 4; ++dm) {
            int dl = 16*dm + l15, sw = (dl & 7) << 4;
            #pragma unroll
            for (int kv = 0; kv < 2; ++kv) {
                half4v a0 = *(const half4v*)((const char*)Vts + dl*128 + ((64*kv + 8*g) ^ sw));
                half4v a1 = *(const half4v*)((const char*)Vts + dl*128 + ((64*kv + 32 + 8*g) ^ sw));
                half8 va;
                #pragma unroll
                for (int e = 0; e < 4; ++e) { va[e] = a0[e]; va[4+e] = a1[e]; }
                #pragma unroll
                for (int nf = 0; nf < 2; ++nf)
                    O[dm][nf] = MFMA16(va, pbf[nf][kv], O[dm][nf]);
            }
        }
        __syncthreads();
    }

    // finalize: scale by 1/l, write m & 1/l
    float inv[2];
    #pragma unroll
    for (int nf = 0; nf < 2; ++nf) {
        inv[nf] = 1.f / l[nf];
        #pragma unroll
        for (int dm = 0; dm < 4; ++dm) O[dm][nf] *= inv[nf];
    }
    if (g == 0) {
        #pragma unroll
        for (int nf = 0; nf < 2; ++nf) {
            int t = t0 + w*32 + 16*nf + l15;
            Ml[(size_t)bh*TLEN + t] = m[nf];
            Il[(size_t)bh*TLEN + t] = inv[nf];
        }
    }

    // epilogue: O^T frags -> LDS [128 t][64 d] f32 -> coalesced f16 global store
    float* ow = (float*)smem;
    #pragma unroll
    for (int nf = 0; nf < 2; ++nf) {
        int tl = w*32 + 16*nf + l15;
        #pragma unroll
        for (int dm = 0; dm < 4; ++dm)
            *(f32x4*)&ow[tl*64 + 16*dm + 4*g] = O[dm][nf];
    }
    __syncthreads();
    {
        int trow = tid >> 1, half = tid & 1;
        const float4* rp = (const float4*)(ow + trow*64 + half*32);
        _Float16* gp = Op + (size_t)((t0+trow)*2 + b)*DD + h*64 + half*32;
        #pragma unroll
        for (int c = 0; c < 4; ++c) {
            float4 x = rp[2*c], y = rp[2*c+1];
            half8 o;
            o[0]=(_Float16)x.x; o[1]=(_Float16)x.y; o[2]=(_Float16)x.z; o[3]=(_Float16)x.w;
            o[4]=(_Float16)y.x; o[5]=(_Float16)y.y; o[6]=(_Float16)y.z; o[7]=(_Float16)y.w;
            ((half8*)gp)[c] = o;
        }
    }
}

// ---------------- attn_avg[b][t][s] = (1/16) sum_h exp(score - m)/l ----------------
// Block: 128t x 128s region, h-loop inside; wave: 32t x 128s. Swapped QK like att_o.
__global__ __launch_bounds__(256) void att_avg(const _Float16* __restrict__ Qp,
        const _Float16* __restrict__ Kp, const float* __restrict__ Ml,
        const float* __restrict__ Il, float* __restrict__ avg) {
    __shared__ char smem[32768];
    _Float16* Ks = (_Float16*)smem;            // [128 s][64 d] swizzled, 16KB
    const int tid = threadIdx.x;
    const int lane = tid & 63, w = tid >> 6;
    const int l15 = lane & 15, g = lane >> 4;
    const int b = blockIdx.z;
    const int t0 = blockIdx.y * 128, s0 = blockIdx.x * 128;

    float acc[8][2][4];
    #pragma unroll
    for (int mf = 0; mf < 8; ++mf)
        #pragma unroll
        for (int nf = 0; nf < 2; ++nf)
            #pragma unroll
            for (int r = 0; r < 4; ++r) acc[mf][nf][r] = 0.f;

    for (int h = 0; h < NHEAD; ++h) {
        const int bh = b*NHEAD + h;
        #pragma unroll
        for (int it = 0; it < 4; ++it) {       // stage K tile 16KB
            int X = (it*256 + tid) * 16;
            int row = X >> 7, xin = X & 127;
            int col2 = swz(row, xin);
            GLD16(Kp + (size_t)((s0+row)*2 + b)*DD + h*64 + (col2>>1), (char*)Ks + X);
        }
        __syncthreads();

        half8 qf[2][2];
        float mm[2], ii[2];
        #pragma unroll
        for (int nf = 0; nf < 2; ++nf) {
            int t = t0 + w*32 + 16*nf + l15;
            #pragma unroll
            for (int kq = 0; kq < 2; ++kq)
                qf[nf][kq] = *(const half8*)(Qp + (size_t)(t*2+b)*DD + h*64 + 8*g + 32*kq);
            mm[nf] = Ml[(size_t)bh*TLEN + t];
            ii[nf] = Il[(size_t)bh*TLEN + t];
        }

        #pragma unroll
        for (int mf = 0; mf < 8; ++mf) {
            int srow = 16*mf + l15, sw = (srow & 7) << 4;
            half8 k0 = *(const half8*)((const char*)Ks + srow*128 + ((16*g) ^ sw));
            half8 k1 = *(const half8*)((const char*)Ks + srow*128 + ((64 + 16*g) ^ sw));
            #pragma unroll
            for (int nf = 0; nf < 2; ++nf) {
                f32x4 z = (f32x4){0.f,0.f,0.f,0.f};
                z = MFMA16(k0, qf[nf][0], z);
                z = MFMA16(k1, qf[nf][1], z);
                #pragma unroll
                for (int r = 0; r < 4; ++r)
                    acc[mf][nf][r] += __expf(z[r] - mm[nf]) * ii[nf];
            }
        }
        __syncthreads();
    }

    // epilogue: two passes (s halves) through LDS for coalesced f32 stores
    const float invh = 1.f / NHEAD;
    float* ow = (float*)smem;                  // per-wave [32 t][64 s] f32, 8KB each
    #pragma unroll
    for (int P = 0; P < 2; ++P) {
        __syncthreads();
        #pragma unroll
        for (int nf = 0; nf < 2; ++nf) {
            int tl = 16*nf + l15;
            #pragma unroll
            for (int mf2 = 0; mf2 < 4; ++mf2) {
                int mf = 4*P + mf2;
                f32x4 v;
                #pragma unroll
                for (int r = 0; r < 4; ++r) v[r] = acc[mf][nf][r] * invh;
                *(f32x4*)&ow[w*2048 + tl*64 + 16*mf2 + 4*g] = v;
            }
        }
        __syncthreads();
        int trow = tid >> 1, half = tid & 1;
        const float4* rp = (const float4*)(ow + (trow>>5)*2048 + (trow&31)*64 + half*32);
        float4* gp = (float4*)(avg + ((size_t)(b*TLEN + t0 + trow))*SLEN + s0 + P*64 + half*32);
        #pragma unroll
        for (int c = 0; c < 8; ++c) gp[c] = rp[c];
    }
}

// ---------------- host launcher ----------------
extern "C" void kernel_launch(void* const* d_in, const int* in_sizes, int n_in,
                              void* d_out, int out_size, void* d_ws, size_t ws_size,
                              hipStream_t stream) {
    (void)in_sizes; (void)n_in; (void)out_size; (void)ws_size;
    const float* query = (const float*)d_in[0];
    const float* key_  = (const float*)d_in[1];
    const float* value = (const float*)d_in[2];
    const float* Wq = (const float*)d_in[3];  const float* bq = (const float*)d_in[4];
    const float* Wk = (const float*)d_in[5];  const float* bk = (const float*)d_in[6];
    const float* Wv = (const float*)d_in[7];  const float* bv = (const float*)d_in[8];
    const float* Wo = (const float*)d_in[9];  const float* bo = (const float*)d_in[10];

    float* out = (float*)d_out;                // Z (4M f32), then avg (8.4M f32)
    char* ws = (char*)d_ws;                    // 67,633,152 bytes used
    _Float16* QF  = (_Float16*)(ws);           // 8MB (reused as Op after gemmQ)
    _Float16* KF  = (_Float16*)(ws + 8388608);
    _Float16* VF  = (_Float16*)(ws + 16777216);
    _Float16* WqF = (_Float16*)(ws + 25165824);
    _Float16* WkF = (_Float16*)(ws + 27262976);
    _Float16* WvF = (_Float16*)(ws + 29360128);
    _Float16* WoF = (_Float16*)(ws + 31457280);
    _Float16* Qp  = (_Float16*)(ws + 33554432);
    _Float16* Kp  = (_Float16*)(ws + 41943040);
    _Float16* Vp  = (_Float16*)(ws + 50331648);
    _Float16* Vt  = (_Float16*)(ws + 58720256);
    float*    Ml  = (float*)(ws + 67108864);
    float*    Il  = (float*)(ws + 67371008);
    _Float16* Op  = QF;                        // alias: QF dead after gemmQ

    const dim3 blk(256);
    convk<<<2048, blk, 0, stream>>>(query, QF, 524288);
    convk<<<2048, blk, 0, stream>>>(key_,  KF, 524288);
    convk<<<2048, blk, 0, stream>>>(value, VF, 524288);
    convk<<<512,  blk, 0, stream>>>(Wq, WqF, 131072);
    convk<<<512,  blk, 0, stream>>>(Wk, WkF, 131072);
    convk<<<512,  blk, 0, stream>>>(Wv, WvF, 131072);
    convk<<<512,  blk, 0, stream>>>(Wo, WoF, 131072);

    const dim3 ggrid(8, 32);                   // N/128, M/128
    gemm16<<<ggrid, blk, 0, stream>>>(QF, WqF, bq, Qp, 0.125f, 0);
    gemm16<<<ggrid, blk, 0, stream>>>(KF, WkF, bk, Kp, 1.0f,   0);
    gemm16<<<ggrid, blk, 0, stream>>>(VF, WvF, bv, Vp, 1.0f,   0);

    transv<<<dim3(32, 32), blk, 0, stream>>>(Vp, Vt);
    att_o<<<dim3(16, 32), blk, 0, stream>>>(Qp, Kp, Vt, Op, Ml, Il);
    att_avg<<<dim3(16, 16, 2), blk, 0, stream>>>(Qp, Kp, Ml, Il, out + 4194304);

    gemm16<<<ggrid, blk, 0, stream>>>(Op, WoF, bo, out, 1.0f, 1);
}

// Round 4
// 321.443 us; speedup vs baseline: 5.9854x; 1.1251x over previous
//
#include <hip/hip_runtime.h>
#include <hip/hip_bf16.h>
#include <math.h>

// Problem constants
#define DD    1024
#define NHEAD 16
#define HDIM  64
#define TLEN  2048
#define SLEN  2048
#define BSZ   2
#define NBH   (BSZ*NHEAD)   // 32
#define GROWS (TLEN*BSZ)    // 4096

typedef _Float16 half8 __attribute__((ext_vector_type(8)));
typedef float f32x4 __attribute__((ext_vector_type(4)));

#define MFMA16(a,b,c) __builtin_amdgcn_mfma_f32_16x16x32_f16((a),(b),(c),0,0,0)

// async global->LDS, 16B per lane. LDS dest linear (wave-uniform base + lane*16).
#define GLD16(g, l) __builtin_amdgcn_global_load_lds( \
    (const __attribute__((address_space(1))) unsigned int*)(g), \
    (__attribute__((address_space(3))) unsigned int*)(l), 16, 0, 0)

// XOR swizzle within a 128-byte row: permutes 16B blocks by row&7 (bijective involution).
__device__ __forceinline__ int swz(int row, int col2) { return col2 ^ ((row & 7) << 4); }

// ---------------- fp32 -> f16 convert, all 7 tensors in one launch ----------------
struct CvtArgs { const float* s[7]; _Float16* d[7]; };

__global__ __launch_bounds__(256) void convall(CvtArgs a) {
    int idx = blockIdx.x * 256 + threadIdx.x;       // half8 group id, 2,097,152 total
    int ai, wi;
    if (idx < 1572864) { ai = idx / 524288; wi = idx - ai * 524288; }
    else { int r = idx - 1572864; ai = 3 + (r >> 17); wi = r & 131071; }
    const float4* s4 = (const float4*)a.s[ai];
    float4 x = s4[2*wi], y = s4[2*wi+1];
    half8 v;
    v[0]=(_Float16)x.x; v[1]=(_Float16)x.y; v[2]=(_Float16)x.z; v[3]=(_Float16)x.w;
    v[4]=(_Float16)y.x; v[5]=(_Float16)y.y; v[6]=(_Float16)y.z; v[7]=(_Float16)y.w;
    *(half8*)&a.d[ai][8*wi] = v;
}

// ---------------- f16 MFMA GEMM body: Y = (A @ W^T + bias) * scale ----------------
// 128x128 tile, BK=64, 4 waves each 64x64 (4x4 16x16x32 frags).
__device__ __forceinline__ void gemm_body(_Float16* As, _Float16* Bs,
        const _Float16* __restrict__ A, const _Float16* __restrict__ Bw,
        const float* __restrict__ bias, void* __restrict__ Yp,
        float scale, int f32out, int m0, int n0) {
    const int tid = threadIdx.x;
    const int lane = tid & 63, w = tid >> 6;
    const int l15 = lane & 15, g = lane >> 4;
    const int wm = (w >> 1) * 64, wn = (w & 1) * 64;

    f32x4 acc[4][4];
    #pragma unroll
    for (int i = 0; i < 4; ++i)
        #pragma unroll
        for (int j = 0; j < 4; ++j) acc[i][j] = (f32x4){0.f,0.f,0.f,0.f};

    for (int kt = 0; kt < DD/64; ++kt) {
        #pragma unroll
        for (int it = 0; it < 4; ++it) {
            int X = (it*256 + tid) * 16;        // byte offset in 16KB tile
            int row = X >> 7, xin = X & 127;    // 128B rows (64 f16)
            GLD16(A  + (size_t)(m0+row)*DD + kt*64 + (xin>>1), (char*)As + X);
            GLD16(Bw + (size_t)(n0+row)*DD + kt*64 + (xin>>1), (char*)Bs + X);
        }
        __syncthreads();
        #pragma unroll
        for (int kq = 0; kq < 2; ++kq) {
            half8 af[4], bf[4];
            #pragma unroll
            for (int i = 0; i < 4; ++i)
                af[i] = *(const half8*)((const char*)As + (wm+16*i+l15)*128 + 16*g + 64*kq);
            #pragma unroll
            for (int j = 0; j < 4; ++j)
                bf[j] = *(const half8*)((const char*)Bs + (wn+16*j+l15)*128 + 16*g + 64*kq);
            #pragma unroll
            for (int i = 0; i < 4; ++i)
                #pragma unroll
                for (int j = 0; j < 4; ++j)
                    acc[i][j] = MFMA16(af[i], bf[j], acc[i][j]);
        }
        __syncthreads();
    }

    #pragma unroll
    for (int j = 0; j < 4; ++j) {
        int c = n0 + wn + 16*j + l15;
        float bj = bias[c];
        #pragma unroll
        for (int i = 0; i < 4; ++i) {
            #pragma unroll
            for (int r = 0; r < 4; ++r) {
                int rr = m0 + wm + 16*i + 4*g + r;
                float y = (acc[i][j][r] + bj) * scale;
                if (f32out) ((float*)Yp)[(size_t)rr*DD + c] = y;
                else        ((_Float16*)Yp)[(size_t)rr*DD + c] = (_Float16)y;
            }
        }
    }
}

// z-merged Q/K/V projection: grid (8, 32, 3)
__global__ __launch_bounds__(256) void gemm_qkv(
        const _Float16* QF, const _Float16* KF, const _Float16* VF,
        const _Float16* WqF, const _Float16* WkF, const _Float16* WvF,
        const float* bq, const float* bk, const float* bv,
        _Float16* Qp, _Float16* Kp, _Float16* Vp) {
    __shared__ _Float16 As[128*64];
    __shared__ _Float16 Bs[128*64];
    const int z = blockIdx.z;
    const _Float16* A  = (z == 0) ? QF  : (z == 1) ? KF  : VF;
    const _Float16* Wm = (z == 0) ? WqF : (z == 1) ? WkF : WvF;
    const float*    bi = (z == 0) ? bq  : (z == 1) ? bk  : bv;
    _Float16*       Y  = (z == 0) ? Qp  : (z == 1) ? Kp  : Vp;
    float scale = (z == 0) ? 0.125f : 1.0f;
    gemm_body(As, Bs, A, Wm, bi, Y, scale, 0, blockIdx.y*128, blockIdx.x*128);
}

// output projection: grid (8, 32)
__global__ __launch_bounds__(256) void gemm_out(const _Float16* __restrict__ A,
        const _Float16* __restrict__ Wm, const float* __restrict__ bi,
        float* __restrict__ Y) {
    __shared__ _Float16 As[128*64];
    __shared__ _Float16 Bs[128*64];
    gemm_body(As, Bs, A, Wm, bi, Y, 1.0f, 1, blockIdx.y*128, blockIdx.x*128);
}

// ---------------- V transpose + k-slot permute: Vp [s*2+b][1024] -> Vt [bh][d][2048] ----------------
// Within each 32-s block, value for source s (u = s&31) is stored at slot
// p = 8*(u>>2 & 3) + (u&3) + 4*((u>>4)&1), so PV A-operand reads are contiguous half8.
__global__ __launch_bounds__(256) void transv(const _Float16* __restrict__ Vp,
                                              _Float16* __restrict__ Vt) {
    __shared__ _Float16 Ts[64*64];   // [s][d] swizzled, 128B rows
    const int tid = threadIdx.x;
    const int s0 = blockIdx.x * 64, bh = blockIdx.y;
    const int b = bh >> 4, h = bh & 15;
    #pragma unroll
    for (int it = 0; it < 2; ++it) {
        int X = (it*256 + tid) * 16;
        int row = X >> 7, xin = X & 127;
        int col2 = swz(row, xin);              // pre-swizzled source
        GLD16(Vp + (size_t)((s0+row)*2 + b)*DD + h*64 + (col2>>1), (char*)Ts + X);
    }
    __syncthreads();
    const int d = tid >> 2, sp = tid & 3;      // sp handles s in [16sp, 16sp+16)
    _Float16* rowp = Vt + ((size_t)bh*64 + d)*SLEN + s0 + 32*(sp>>1) + 4*(sp&1);
    #pragma unroll
    for (int j = 0; j < 4; ++j) {
        unsigned short us[4];
        #pragma unroll
        for (int e = 0; e < 4; ++e) {
            int s = 16*sp + 4*j + e;
            us[e] = *(const unsigned short*)((const char*)Ts + s*128 + swz(s, d*2));
        }
        uint2 pk = make_uint2(us[0] | ((unsigned)us[1] << 16),
                              us[2] | ((unsigned)us[3] << 16));
        *(uint2*)(rowp + 8*j) = pk;            // slot base p = 8j + 4*(sp&1)
    }
}

// ---------------- Flash attention: O = softmax(QK^T)V -> Op f16, Ml, Il ----------------
// 64 t-rows/block, 4 waves x 16 t. Swapped QK^T: sc = mfma(K,Q) -> lane t=lane&15,
// s = 16mf + 4g + r. P packed to f16 slots p=8g+e; Vt pre-permuted so PV A-read is b128.
__global__ __launch_bounds__(256) void att_o(const _Float16* __restrict__ Qp,
        const _Float16* __restrict__ Kp, const _Float16* __restrict__ Vt,
        _Float16* __restrict__ Op, float* __restrict__ Ml, float* __restrict__ Il) {
    __shared__ char smem[16384];
    _Float16* Ks  = (_Float16*)smem;            // [64 s][64 d] swizzled, 8KB
    _Float16* Vts = (_Float16*)(smem + 8192);   // [64 d][64 s-perm] swizzled, 8KB
    const int tid = threadIdx.x;
    const int lane = tid & 63, w = tid >> 6;
    const int l15 = lane & 15, g = lane >> 4;
    const int bh = blockIdx.y, b = bh >> 4, h = bh & 15;
    const int t0 = blockIdx.x * 64;
    const int t = t0 + w*16 + l15;

    half8 qf[2];
    #pragma unroll
    for (int kq = 0; kq < 2; ++kq)
        qf[kq] = *(const half8*)(Qp + (size_t)(t*2+b)*DD + h*64 + 8*g + 32*kq);

    float m = -1e30f, l = 0.f;
    f32x4 O[4];
    #pragma unroll
    for (int dm = 0; dm < 4; ++dm) O[dm] = (f32x4){0.f,0.f,0.f,0.f};

    for (int s0 = 0; s0 < SLEN; s0 += 64) {
        #pragma unroll
        for (int it = 0; it < 2; ++it) {       // stage K (8KB) + Vt (8KB)
            int X = (it*256 + tid) * 16;
            int row = X >> 7, xin = X & 127;
            int col2 = swz(row, xin);
            GLD16(Kp + (size_t)((s0+row)*2 + b)*DD + h*64 + (col2>>1), (char*)Ks + X);
            GLD16(Vt + ((size_t)bh*64 + row)*SLEN + s0 + (col2>>1), (char*)Vts + X);
        }
        __syncthreads();

        f32x4 sc[4];
        #pragma unroll
        for (int mf = 0; mf < 4; ++mf) {
            int srow = 16*mf + l15, sw = (srow & 7) << 4;
            half8 k0 = *(const half8*)((const char*)Ks + srow*128 + ((16*g) ^ sw));
            half8 k1 = *(const half8*)((const char*)Ks + srow*128 + ((64 + 16*g) ^ sw));
            f32x4 z = (f32x4){0.f,0.f,0.f,0.f};
            z = MFMA16(k0, qf[0], z);
            z = MFMA16(k1, qf[1], z);
            sc[mf] = z;
        }

        // online softmax (t per lane; s spread over g, mf, r)
        float mx = -1e30f;
        #pragma unroll
        for (int mf = 0; mf < 4; ++mf)
            #pragma unroll
            for (int r = 0; r < 4; ++r) mx = fmaxf(mx, sc[mf][r]);
        mx = fmaxf(mx, __shfl_xor(mx, 16));
        mx = fmaxf(mx, __shfl_xor(mx, 32));
        float mn = fmaxf(m, mx);
        float corr = __expf(m - mn);
        float pr[4][4];
        float rs = 0.f;
        #pragma unroll
        for (int mf = 0; mf < 4; ++mf)
            #pragma unroll
            for (int r = 0; r < 4; ++r) {
                pr[mf][r] = __expf(sc[mf][r] - mn);
                rs += pr[mf][r];
            }
        rs += __shfl_xor(rs, 16);
        rs += __shfl_xor(rs, 32);
        l = l * corr + rs;
        m = mn;
        #pragma unroll
        for (int dm = 0; dm < 4; ++dm) O[dm] *= corr;

        half8 pbf[2];
        #pragma unroll
        for (int kv = 0; kv < 2; ++kv) {
            half8 pb;
            #pragma unroll
            for (int e = 0; e < 4; ++e) {
                pb[e]   = (_Float16)pr[2*kv][e];
                pb[4+e] = (_Float16)pr[2*kv+1][e];
            }
            pbf[kv] = pb;
        }

        // PV: O^T[d][t] += V^T[d][s] * P^T[s][t]; Vt pre-permuted -> contiguous b128
        #pragma unroll
        for (int dm = 0; dm < 4; ++dm) {
            int dl = 16*dm + l15, sw = (dl & 7) << 4;
            #pragma unroll
            for (int kv = 0; kv < 2; ++kv) {
                half8 va = *(const half8*)((const char*)Vts + dl*128 + ((64*kv + 16*g) ^ sw));
                O[dm] = MFMA16(va, pbf[kv], O[dm]);
            }
        }
        __syncthreads();
    }

    float inv = 1.f / l;
    #pragma unroll
    for (int dm = 0; dm < 4; ++dm) O[dm] *= inv;
    if (g == 0) {
        Ml[(size_t)bh*TLEN + t] = m;
        Il[(size_t)bh*TLEN + t] = inv;
    }

    // epilogue: O^T frags -> LDS [64 t][64 d] f32 -> coalesced f16 store
    float* ow = (float*)smem;
    {
        int tl = w*16 + l15;
        #pragma unroll
        for (int dm = 0; dm < 4; ++dm)
            *(f32x4*)&ow[tl*64 + 16*dm + 4*g] = O[dm];
    }
    __syncthreads();
    {
        int trow = tid >> 2, q = tid & 3;
        const float4* rp = (const float4*)(ow + trow*64 + q*16);
        _Float16* gp = Op + (size_t)((t0+trow)*2 + b)*DD + h*64 + q*16;
        #pragma unroll
        for (int c = 0; c < 2; ++c) {
            float4 x = rp[2*c], y = rp[2*c+1];
            half8 o;
            o[0]=(_Float16)x.x; o[1]=(_Float16)x.y; o[2]=(_Float16)x.z; o[3]=(_Float16)x.w;
            o[4]=(_Float16)y.x; o[5]=(_Float16)y.y; o[6]=(_Float16)y.z; o[7]=(_Float16)y.w;
            ((half8*)gp)[c] = o;
        }
    }
}

// ---------------- attn_avg[b][t][s] = (1/16) sum_h exp(score - m) * il ----------------
// 64t x 128s per block, h-loop inside (no atomics). grid (16, 32, 2).
__global__ __launch_bounds__(256) void att_avg(const _Float16* __restrict__ Qp,
        const _Float16* __restrict__ Kp, const float* __restrict__ Ml,
        const float* __restrict__ Il, float* __restrict__ avg) {
    __shared__ char smem[32768];
    _Float16* Ks = (_Float16*)smem;            // [128 s][64 d] swizzled, 16KB
    const int tid = threadIdx.x;
    const int lane = tid & 63, w = tid >> 6;
    const int l15 = lane & 15, g = lane >> 4;
    const int b = blockIdx.z;
    const int t0 = blockIdx.y * 64, s0 = blockIdx.x * 128;
    const int t = t0 + w*16 + l15;

    float acc[8][4];
    #pragma unroll
    for (int mf = 0; mf < 8; ++mf)
        #pragma unroll
        for (int r = 0; r < 4; ++r) acc[mf][r] = 0.f;

    for (int h = 0; h < NHEAD; ++h) {
        const int bh = b*NHEAD + h;
        __syncthreads();                       // prev iter frag reads done
        #pragma unroll
        for (int it = 0; it < 4; ++it) {       // stage K tile 16KB
            int X = (it*256 + tid) * 16;
            int row = X >> 7, xin = X & 127;
            int col2 = swz(row, xin);
            GLD16(Kp + (size_t)((s0+row)*2 + b)*DD + h*64 + (col2>>1), (char*)Ks + X);
        }
        __syncthreads();

        half8 qf[2];
        #pragma unroll
        for (int kq = 0; kq < 2; ++kq)
            qf[kq] = *(const half8*)(Qp + (size_t)(t*2+b)*DD + h*64 + 8*g + 32*kq);
        float mm = Ml[(size_t)bh*TLEN + t];
        float ii = Il[(size_t)bh*TLEN + t];

        #pragma unroll
        for (int mf = 0; mf < 8; ++mf) {
            int srow = 16*mf + l15, sw = (srow & 7) << 4;
            half8 k0 = *(const half8*)((const char*)Ks + srow*128 + ((16*g) ^ sw));
            half8 k1 = *(const half8*)((const char*)Ks + srow*128 + ((64 + 16*g) ^ sw));
            f32x4 z = (f32x4){0.f,0.f,0.f,0.f};
            z = MFMA16(k0, qf[0], z);
            z = MFMA16(k1, qf[1], z);
            #pragma unroll
            for (int r = 0; r < 4; ++r)
                acc[mf][r] += __expf(z[r] - mm) * ii;
        }
    }

    __syncthreads();
    const float invh = 1.f / NHEAD;
    float* ow = (float*)smem;                  // [64 t][128 s] f32 = 32KB
    {
        int tl = w*16 + l15;
        #pragma unroll
        for (int mf = 0; mf < 8; ++mf) {
            f32x4 v;
            #pragma unroll
            for (int r = 0; r < 4; ++r) v[r] = acc[mf][r] * invh;
            *(f32x4*)&ow[tl*128 + 16*mf + 4*g] = v;
        }
    }
    __syncthreads();
    {
        int trow = tid >> 2, q = tid & 3;
        const float4* rp = (const float4*)(ow + trow*128 + q*32);
        float4* gp = (float4*)(avg + ((size_t)(b*TLEN + t0 + trow))*SLEN + s0 + q*32);
        #pragma unroll
        for (int c = 0; c < 8; ++c) gp[c] = rp[c];
    }
}

// ---------------- host launcher ----------------
extern "C" void kernel_launch(void* const* d_in, const int* in_sizes, int n_in,
                              void* d_out, int out_size, void* d_ws, size_t ws_size,
                              hipStream_t stream) {
    (void)in_sizes; (void)n_in; (void)out_size; (void)ws_size;
    const float* query = (const float*)d_in[0];
    const float* key_  = (const float*)d_in[1];
    const float* value = (const float*)d_in[2];
    const float* Wq = (const float*)d_in[3];  const float* bq = (const float*)d_in[4];
    const float* Wk = (const float*)d_in[5];  const float* bk = (const float*)d_in[6];
    const float* Wv = (const float*)d_in[7];  const float* bv = (const float*)d_in[8];
    const float* Wo = (const float*)d_in[9];  const float* bo = (const float*)d_in[10];

    float* out = (float*)d_out;                // Z (4M f32), then avg (8.4M f32)
    char* ws = (char*)d_ws;                    // 67,633,152 bytes used
    _Float16* QF  = (_Float16*)(ws);           // 8MB (reused as Op after gemm_qkv)
    _Float16* KF  = (_Float16*)(ws + 8388608);
    _Float16* VF  = (_Float16*)(ws + 16777216);
    _Float16* WqF = (_Float16*)(ws + 25165824);
    _Float16* WkF = (_Float16*)(ws + 27262976);
    _Float16* WvF = (_Float16*)(ws + 29360128);
    _Float16* WoF = (_Float16*)(ws + 31457280);
    _Float16* Qp  = (_Float16*)(ws + 33554432);
    _Float16* Kp  = (_Float16*)(ws + 41943040);
    _Float16* Vp  = (_Float16*)(ws + 50331648);
    _Float16* Vt  = (_Float16*)(ws + 58720256);
    float*    Ml  = (float*)(ws + 67108864);
    float*    Il  = (float*)(ws + 67371008);
    _Float16* Op  = QF;                        // alias: QF dead after gemm_qkv

    const dim3 blk(256);

    CvtArgs ca;
    ca.s[0]=query; ca.s[1]=key_; ca.s[2]=value; ca.s[3]=Wq; ca.s[4]=Wk; ca.s[5]=Wv; ca.s[6]=Wo;
    ca.d[0]=QF;    ca.d[1]=KF;   ca.d[2]=VF;    ca.d[3]=WqF; ca.d[4]=WkF; ca.d[5]=WvF; ca.d[6]=WoF;
    convall<<<8192, blk, 0, stream>>>(ca);

    gemm_qkv<<<dim3(8, 32, 3), blk, 0, stream>>>(QF, KF, VF, WqF, WkF, WvF,
                                                 bq, bk, bv, Qp, Kp, Vp);

    transv<<<dim3(32, 32), blk, 0, stream>>>(Vp, Vt);
    att_o<<<dim3(32, 32), blk, 0, stream>>>(Qp, Kp, Vt, Op, Ml, Il);
    att_avg<<<dim3(16, 32, 2), blk, 0, stream>>>(Qp, Kp, Ml, Il, out + 4194304);

    gemm_out<<<dim3(8, 32), blk, 0, stream>>>(Op, WoF, bo, out);
}